// Round 1
// baseline (4557.809 us; speedup 1.0000x reference)
//
#include <hip/hip_runtime.h>

#define B_ 64
#define T_ 256
#define D_ 300
#define DP_ 320
#define H_ 256
#define G_ 1024
#define N_ 8

typedef unsigned int u32;
typedef unsigned short u16;
typedef __attribute__((ext_vector_type(8))) short short8;
typedef __attribute__((ext_vector_type(4))) float f32x4;
typedef __attribute__((ext_vector_type(4))) u32 u32x4;

__device__ __forceinline__ u16 f2bf(float f){
  union {float f; u32 u;} v; v.f = f;
  u32 r = (v.u + 0x7fffu + ((v.u>>16)&1u)) >> 16;
  return (u16)r;
}
__device__ __forceinline__ float bflo(u32 u){
  union {u32 u; float f;} v; v.u = u<<16; return v.f;
}
__device__ __forceinline__ float bfhi(u32 u){
  union {u32 u; float f;} v; v.u = u & 0xffff0000u; return v.f;
}
__device__ __forceinline__ float sigm(float x){ return 1.0f/(1.0f+__expf(-x)); }
__device__ __forceinline__ float tanh_(float x){ return 2.0f/(1.0f+__expf(-2.0f*x)) - 1.0f; }

// ---------------- K1: mixture coefficients c[b][8] ----------------
__global__ void __launch_bounds__(64) k_coef(
    const int* __restrict__ uidx, const int* __restrict__ iidx,
    const float* __restrict__ uemb, const float* __restrict__ iemb,
    const float* __restrict__ W1, const float* __restrict__ b1,
    const float* __restrict__ W2, float* __restrict__ coef)
{
  __shared__ float q[128];
  __shared__ float hid[64];
  __shared__ float lg[8];
  int b = blockIdx.x, t = threadIdx.x;
  int u = uidx[b], it = iidx[b];
  q[t]      = uemb[(size_t)u*64 + t];
  q[64 + t] = iemb[(size_t)it*64 + t];
  __syncthreads();
  float s = b1[t];
  for (int j = 0; j < 128; ++j) s = fmaf(q[j], W1[j*64 + t], s);
  hid[t] = tanhf(s);
  __syncthreads();
  if (t < 8) {
    float s2 = 0.f;
    for (int j = 0; j < 64; ++j) s2 = fmaf(hid[j], W2[j*8 + t], s2);
    lg[t] = s2;
  }
  __syncthreads();
  if (t == 0) {
    float mx = lg[0];
    for (int n = 1; n < 8; ++n) mx = fmaxf(mx, lg[n]);
    float e[8], den = 0.f;
    for (int n = 0; n < 8; ++n){ e[n] = __expf(lg[n]-mx); den += e[n]; }
    for (int n = 0; n < 8; ++n) coef[b*8+n] = e[n]/den;
  }
}

// ---------------- K2a: mix Whh (+bias) into packed blob ----------------
// wblob layout: [chain(128)][tid2(512)][q(256)] u32.
//   q in [0,96):   row 2*tid2,   cols (2q, 2q+1)      (lo,hi bf16)
//   q in [96,192): row 2*tid2+1, cols (2(q-96), +1)
//   q in [192,256): col 192+(q-192), rows (2*tid2 lo, 2*tid2+1 hi)
__global__ void __launch_bounds__(256) k_mix_whh(
    const float* __restrict__ Whh_f, const float* __restrict__ Whh_r,
    const float* __restrict__ bias_f, const float* __restrict__ bias_r,
    const float* __restrict__ coef, u32* __restrict__ wblob, float* __restrict__ bias_m)
{
  int gblk = blockIdx.x;   // 0..127, 8 rows each
  int dir  = blockIdx.y;
  int tid  = threadIdx.x;
  const float* Wsel = dir ? Whh_r : Whh_f;
  const float* bsel = dir ? bias_r : bias_f;
  __shared__ float bs[N_][8][H_];   // 64 KB
  for (int v = 0; v < 64; ++v){
    int i = v*256 + tid;
    int n = i >> 11, gl = (i >> 8) & 7, c = i & 255;
    bs[n][gl][c] = Wsel[((size_t)n*G_ + gblk*8 + gl)*H_ + c];
  }
  __syncthreads();
  int p = tid >> 6, s = tid & 63;     // pair p in [0,4), s in [0,64)
  float bw[4][2][8];
  #pragma unroll
  for (int uu = 0; uu < 4; ++uu){
    int q = 64*uu + s;
    int lr0, lr1, c0, c1;
    if (q < 192){ int r = q/96, m = q%96; lr0 = 2*p + r; lr1 = lr0; c0 = 2*m; c1 = 2*m+1; }
    else        { lr0 = 2*p; lr1 = 2*p+1; c0 = q; c1 = q; }
    #pragma unroll
    for (int n = 0; n < 8; ++n){ bw[uu][0][n] = bs[n][lr0][c0]; bw[uu][1][n] = bs[n][lr1][c1]; }
  }
  int tid2g = gblk*4 + p;
  for (int b = 0; b < B_; ++b){
    float c8[8];
    #pragma unroll
    for (int n = 0; n < 8; ++n) c8[n] = coef[b*8+n];
    int chain = dir*B_ + b;
    u32* wp = wblob + ((size_t)chain*512 + tid2g)*256;
    #pragma unroll
    for (int uu = 0; uu < 4; ++uu){
      int q = 64*uu + s;
      float w0 = 0.f, w1 = 0.f;
      #pragma unroll
      for (int n = 0; n < 8; ++n){ w0 = fmaf(c8[n], bw[uu][0][n], w0); w1 = fmaf(c8[n], bw[uu][1][n], w1); }
      wp[q] = (u32)f2bf(w0) | ((u32)f2bf(w1) << 16);
    }
    if (tid < 8){
      float bb = 0.f;
      #pragma unroll
      for (int n = 0; n < 8; ++n) bb = fmaf(c8[n], bsel[n*G_ + gblk*8 + tid], bb);
      bias_m[(size_t)chain*G_ + gblk*8 + tid] = bb;
    }
  }
}

// ---------------- K2b: mix Wih into bf16 [dir][b][g][320] (zero-padded) ----------------
__global__ void __launch_bounds__(256) k_mix_wi(
    const float* __restrict__ Wih_f, const float* __restrict__ Wih_r,
    const float* __restrict__ coef, u32* __restrict__ WimU)
{
  int gblk = blockIdx.x;   // 0..127, 8 rows each
  int dir  = blockIdx.y;
  int tid  = threadIdx.x;
  const float* Wsel = dir ? Wih_r : Wih_f;
  __shared__ float bs[N_][8][D_];   // 76.8 KB
  for (int v = 0; v < 75; ++v){
    int i = v*256 + tid;            // < 19200
    int n = i/2400, rem = i%2400, gl = rem/300, c = rem%300;
    bs[n][gl][c] = Wsel[((size_t)n*G_ + gblk*8 + gl)*D_ + c];
  }
  __syncthreads();
  float bw[5][2][8];
  int rowv[5], cpv[5];
  #pragma unroll
  for (int v = 0; v < 5; ++v){
    int idx = v*256 + tid;          // < 1280
    int row = idx/160, cp = idx%160;
    rowv[v] = row; cpv[v] = cp;
    #pragma unroll
    for (int n = 0; n < 8; ++n){
      bw[v][0][n] = (cp < 150) ? bs[n][row][2*cp]   : 0.f;
      bw[v][1][n] = (cp < 150) ? bs[n][row][2*cp+1] : 0.f;
    }
  }
  for (int b = 0; b < B_; ++b){
    float c8[8];
    #pragma unroll
    for (int n = 0; n < 8; ++n) c8[n] = coef[b*8+n];
    #pragma unroll
    for (int v = 0; v < 5; ++v){
      float w0 = 0.f, w1 = 0.f;
      #pragma unroll
      for (int n = 0; n < 8; ++n){ w0 = fmaf(c8[n], bw[v][0][n], w0); w1 = fmaf(c8[n], bw[v][1][n], w1); }
      WimU[(((size_t)(dir*B_+b)*G_ + gblk*8 + rowv[v])*160) + cpv[v]] = (u32)f2bf(w0) | ((u32)f2bf(w1) << 16);
    }
  }
}

// ---------------- K2c: x -> bf16, padded to 320 ----------------
__global__ void __launch_bounds__(256) k_xpad(const float* __restrict__ x, u32* __restrict__ xpadU)
{
  int o = blockIdx.x*256 + threadIdx.x;   // < 64*256*160
  int bt = o/160, cp = o%160;
  float v0 = (cp < 150) ? x[(size_t)bt*D_ + 2*cp]   : 0.f;
  float v1 = (cp < 150) ? x[(size_t)bt*D_ + 2*cp+1] : 0.f;
  xpadU[o] = (u32)f2bf(v0) | ((u32)f2bf(v1) << 16);
}

// ---------------- K3: xproj[dir][b][t][g] (bf16) = xpad[b] @ Wim[dir][b]^T ----------------
__global__ void __launch_bounds__(256,2) k_gemm(
    const u16* __restrict__ xpad, const u16* __restrict__ Wim, u16* __restrict__ xproj)
{
  int bx = blockIdx.x;            // 16: tt = bx>>3 (2), tg = bx&7 (8)
  int b  = blockIdx.y, dir = blockIdx.z;
  int tt = bx >> 3, tg = bx & 7;
  int tid = threadIdx.x;
  int wid = tid >> 6, lane = tid & 63;
  int wr = wid >> 1, wc = wid & 1;
  __shared__ u16 As[128][72];
  __shared__ u16 Bs[128][72];
  const u16* Ap = xpad + ((size_t)b*T_ + tt*128)*DP_;
  const u16* Bp = Wim + (((size_t)dir*B_ + b)*G_ + tg*128)*DP_;
  f32x4 acc[4][4];
  #pragma unroll
  for (int i = 0; i < 4; ++i)
    #pragma unroll
    for (int j = 0; j < 4; ++j) acc[i][j] = (f32x4){0.f,0.f,0.f,0.f};
  for (int kt = 0; kt < 5; ++kt){
    int k0 = kt*64;
    #pragma unroll
    for (int i = 0; i < 4; ++i){
      int ci = i*256 + tid;
      int row = ci >> 3, cc = (ci & 7)*8;
      *(u32x4*)&As[row][cc] = *(const u32x4*)(Ap + (size_t)row*DP_ + k0 + cc);
      *(u32x4*)&Bs[row][cc] = *(const u32x4*)(Bp + (size_t)row*DP_ + k0 + cc);
    }
    __syncthreads();
    #pragma unroll
    for (int kk = 0; kk < 2; ++kk){
      short8 af[4], bfr[4];
      #pragma unroll
      for (int mi = 0; mi < 4; ++mi) af[mi]  = *(const short8*)&As[wr*64 + mi*16 + (lane&15)][kk*32 + (lane>>4)*8];
      #pragma unroll
      for (int ni = 0; ni < 4; ++ni) bfr[ni] = *(const short8*)&Bs[wc*64 + ni*16 + (lane&15)][kk*32 + (lane>>4)*8];
      #pragma unroll
      for (int mi = 0; mi < 4; ++mi)
        #pragma unroll
        for (int ni = 0; ni < 4; ++ni)
          acc[mi][ni] = __builtin_amdgcn_mfma_f32_16x16x32_bf16(af[mi], bfr[ni], acc[mi][ni], 0,0,0);
    }
    __syncthreads();
  }
  int r4 = (lane >> 4)*4, cg = lane & 15;
  #pragma unroll
  for (int mi = 0; mi < 4; ++mi)
    #pragma unroll
    for (int ni = 0; ni < 4; ++ni)
      #pragma unroll
      for (int j = 0; j < 4; ++j){
        int t = tt*128 + wr*64 + mi*16 + r4 + j;
        int g = tg*128 + wc*64 + ni*16 + cg;
        xproj[(((size_t)dir*B_ + b)*T_ + t)*G_ + g] = f2bf(acc[mi][ni][j]);
      }
}

// ---------------- K4: recurrence, one chain (b,dir) per workgroup ----------------
__global__ void __launch_bounds__(512,2) k_rec(
    const u32* __restrict__ wblob, const float* __restrict__ bias_m,
    const u32* __restrict__ xprojU, const int* __restrict__ length,
    float* __restrict__ out)
{
  int chain = blockIdx.x;
  int dir = chain >> 6, b = chain & 63;
  int tid = threadIdx.x;                 // 0..511, gates 2*tid, 2*tid+1
  __shared__ u32 wlds[64][512];          // 128 KB: cols 192..255, packed (g0,g1)
  __shared__ float h_lds[256];
  __shared__ float c_lds[256];
  __shared__ float gates[1024];
  const u32* wb = wblob + ((size_t)chain*512 + tid)*256;
  u32 wr0[96], wr1[96];
  #pragma unroll
  for (int i = 0; i < 24; ++i){
    u32x4 v = ((const u32x4*)wb)[i];
    wr0[4*i] = v.x; wr0[4*i+1] = v.y; wr0[4*i+2] = v.z; wr0[4*i+3] = v.w;
  }
  #pragma unroll
  for (int i = 0; i < 24; ++i){
    u32x4 v = ((const u32x4*)wb)[24+i];
    wr1[4*i] = v.x; wr1[4*i+1] = v.y; wr1[4*i+2] = v.z; wr1[4*i+3] = v.w;
  }
  #pragma unroll
  for (int i = 0; i < 16; ++i){
    u32x4 v = ((const u32x4*)wb)[48+i];
    wlds[4*i][tid] = v.x; wlds[4*i+1][tid] = v.y; wlds[4*i+2][tid] = v.z; wlds[4*i+3][tid] = v.w;
  }
  float2 bb = *(const float2*)&bias_m[(size_t)chain*G_ + 2*tid];
  if (tid < 256){ h_lds[tid] = 0.f; c_lds[tid] = 0.f; }
  int len = length[b];
  const u32* xp = xprojU + (size_t)chain*T_*512;
  float* outp = out + ((size_t)b*T_)*512 + dir*H_;
  __syncthreads();
  for (int step = 0; step < len; ++step){
    int t = dir ? (len-1-step) : step;
    u32 xv = xp[(size_t)t*512 + tid];
    float acc0 = bb.x + bflo(xv);
    float acc1 = bb.y + bfhi(xv);
    #pragma unroll
    for (int ch = 0; ch < 6; ++ch){
      float hv[32];
      #pragma unroll
      for (int e = 0; e < 8; ++e){
        f32x4 h4 = *(const f32x4*)&h_lds[ch*32 + 4*e];
        hv[4*e] = h4.x; hv[4*e+1] = h4.y; hv[4*e+2] = h4.z; hv[4*e+3] = h4.w;
      }
      #pragma unroll
      for (int e = 0; e < 16; ++e){
        u32 u0 = wr0[ch*16+e], u1 = wr1[ch*16+e];
        acc0 = fmaf(bflo(u0), hv[2*e],   acc0);
        acc0 = fmaf(bfhi(u0), hv[2*e+1], acc0);
        acc1 = fmaf(bflo(u1), hv[2*e],   acc1);
        acc1 = fmaf(bfhi(u1), hv[2*e+1], acc1);
      }
    }
    #pragma unroll
    for (int cb = 0; cb < 16; ++cb){
      f32x4 h4 = *(const f32x4*)&h_lds[192 + 4*cb];
      u32 w0 = wlds[4*cb][tid], w1 = wlds[4*cb+1][tid], w2 = wlds[4*cb+2][tid], w3 = wlds[4*cb+3][tid];
      acc0 = fmaf(bflo(w0), h4.x, acc0); acc1 = fmaf(bfhi(w0), h4.x, acc1);
      acc0 = fmaf(bflo(w1), h4.y, acc0); acc1 = fmaf(bfhi(w1), h4.y, acc1);
      acc0 = fmaf(bflo(w2), h4.z, acc0); acc1 = fmaf(bfhi(w2), h4.z, acc1);
      acc0 = fmaf(bflo(w3), h4.w, acc0); acc1 = fmaf(bfhi(w3), h4.w, acc1);
    }
    float2 g2; g2.x = acc0; g2.y = acc1;
    *(float2*)&gates[2*tid] = g2;
    __syncthreads();
    if (tid < 256){
      float ig = gates[tid], fg = gates[256+tid], gg = gates[512+tid], og = gates[768+tid];
      float i_ = sigm(ig), f_ = sigm(fg), gt = tanh_(gg), o_ = sigm(og);
      float cn = fmaf(f_, c_lds[tid], i_*gt);
      float hy = o_ * tanh_(cn);
      c_lds[tid] = cn; h_lds[tid] = hy;
      outp[(size_t)t*512 + tid] = hy;
    }
    __syncthreads();
  }
}

extern "C" void kernel_launch(void* const* d_in, const int* in_sizes, int n_in,
                              void* d_out, int out_size, void* d_ws, size_t ws_size,
                              hipStream_t stream)
{
  const float* x      = (const float*)d_in[0];
  const int*   length = (const int*)d_in[1];
  const int*   uidx   = (const int*)d_in[2];
  const int*   iidx   = (const int*)d_in[3];
  const float* uemb   = (const float*)d_in[4];
  const float* iemb   = (const float*)d_in[5];
  const float* W1     = (const float*)d_in[6];
  const float* b1     = (const float*)d_in[7];
  const float* W2     = (const float*)d_in[8];
  const float* Wih    = (const float*)d_in[9];
  const float* Whh    = (const float*)d_in[10];
  const float* bias   = (const float*)d_in[11];
  const float* Wih_r  = (const float*)d_in[12];
  const float* Whh_r  = (const float*)d_in[13];
  const float* bias_r = (const float*)d_in[14];
  float* out = (float*)d_out;
  char* ws = (char*)d_ws;

  float* coef   = (float*)(ws + 0);              //   2,048
  float* bias_m = (float*)(ws + 2048);           // 524,288
  u32*   wblob  = (u32*)  (ws + 526336);         //  67,108,864
  u16*   Wim    = (u16*)  (ws + 67635200);       //  83,886,080
  u16*   xpad   = (u16*)  (ws + 151521280);      //  10,485,760
  u16*   xproj  = (u16*)  (ws + 162007040);      //  67,108,864  -> total 229,115,904

  hipMemsetAsync(d_out, 0, (size_t)out_size*sizeof(float), stream);
  if (ws_size < 229115904ull) return;  // fail loudly (all-zero output) if workspace too small

  hipLaunchKernelGGL(k_coef,    dim3(64),       dim3(64),  0, stream, uidx, iidx, uemb, iemb, W1, b1, W2, coef);
  hipLaunchKernelGGL(k_mix_whh, dim3(128,2),    dim3(256), 0, stream, Whh, Whh_r, bias, bias_r, coef, wblob, bias_m);
  hipLaunchKernelGGL(k_mix_wi,  dim3(128,2),    dim3(256), 0, stream, Wih, Wih_r, coef, (u32*)Wim);
  hipLaunchKernelGGL(k_xpad,    dim3(10240),    dim3(256), 0, stream, x, (u32*)xpad);
  hipLaunchKernelGGL(k_gemm,    dim3(16,64,2),  dim3(256), 0, stream, xpad, Wim, xproj);
  hipLaunchKernelGGL(k_rec,     dim3(128),      dim3(512), 0, stream, wblob, bias_m, (const u32*)xproj, length, out);
}

// Round 3
// 852.974 us; speedup vs baseline: 5.3434x; 5.3434x over previous
//
#include <hip/hip_runtime.h>

#define B_ 64
#define T_ 256
#define D_ 300
#define DP_ 320
#define H_ 256
#define G_ 1024
#define N_ 8

typedef unsigned int u32;
typedef unsigned short u16;
typedef __attribute__((ext_vector_type(8))) short short8;
typedef __attribute__((ext_vector_type(4))) float f32x4;
typedef __attribute__((ext_vector_type(4))) u32 u32x4;
typedef __attribute__((ext_vector_type(2))) u32 u32x2;
typedef _Float16 h2 __attribute__((ext_vector_type(2)));
typedef __fp16 fp16x2 __attribute__((ext_vector_type(2)));

__device__ __forceinline__ u16 f2bf(float f){
  union {float f; u32 u;} v; v.f = f;
  u32 r = (v.u + 0x7fffu + ((v.u>>16)&1u)) >> 16;
  return (u16)r;
}
__device__ __forceinline__ float bflo(u32 u){
  union {u32 u; float f;} v; v.u = u<<16; return v.f;
}
__device__ __forceinline__ float bfhi(u32 u){
  union {u32 u; float f;} v; v.u = u & 0xffff0000u; return v.f;
}
__device__ __forceinline__ float sigm(float x){ return 1.0f/(1.0f+__expf(-x)); }
__device__ __forceinline__ float tanh_(float x){ return 2.0f/(1.0f+__expf(-2.0f*x)) - 1.0f; }

__device__ __forceinline__ float fdot2(u32 a, u32 b, float c){
  union { u32 u; h2 h; } ua, ub; ua.u = a; ub.u = b;
#if __has_builtin(__builtin_amdgcn_fdot2)
  return __builtin_amdgcn_fdot2(ua.h, ub.h, c, false);
#else
  return c + (float)ua.h.x*(float)ub.h.x + (float)ua.h.y*(float)ub.h.y;
#endif
}
__device__ __forceinline__ u32 pkf16(float a, float b){
  union { fp16x2 h; u32 u; } v; v.h = __builtin_amdgcn_cvt_pkrtz(a, b); return v.u;
}

// ---------------- K1: mixture coefficients c[b][8] ----------------
__global__ void __launch_bounds__(64) k_coef(
    const int* __restrict__ uidx, const int* __restrict__ iidx,
    const float* __restrict__ uemb, const float* __restrict__ iemb,
    const float* __restrict__ W1, const float* __restrict__ b1,
    const float* __restrict__ W2, float* __restrict__ coef)
{
  __shared__ float q[128];
  __shared__ float hid[64];
  __shared__ float lg[8];
  int b = blockIdx.x, t = threadIdx.x;
  int u = uidx[b], it = iidx[b];
  q[t]      = uemb[(size_t)u*64 + t];
  q[64 + t] = iemb[(size_t)it*64 + t];
  __syncthreads();
  float s = b1[t];
  for (int j = 0; j < 128; ++j) s = fmaf(q[j], W1[j*64 + t], s);
  hid[t] = tanhf(s);
  __syncthreads();
  if (t < 8) {
    float s2 = 0.f;
    for (int j = 0; j < 64; ++j) s2 = fmaf(hid[j], W2[j*8 + t], s2);
    lg[t] = s2;
  }
  __syncthreads();
  if (t == 0) {
    float mx = lg[0];
    for (int n = 1; n < 8; ++n) mx = fmaxf(mx, lg[n]);
    float e[8], den = 0.f;
    for (int n = 0; n < 8; ++n){ e[n] = __expf(lg[n]-mx); den += e[n]; }
    for (int n = 0; n < 8; ++n) coef[b*8+n] = e[n]/den;
  }
}

// ---------------- K2a: mix Whh (+bias) into packed f16 blobs ----------------
// blobA (register part, cols 0..191 as pairs p=0..95):
//   layout [chain][i(48)][tid(512)][e(4)] u32, where k=4i+e, p=k>>1, gatepar=k&1,
//   thread tid owns gates (2*tid, 2*tid+1).
// blobB (LDS part, cols 192..255 as pairs p=96..127):
//   layout [chain][q(32)][gate(1024)] u32, q=p-96.
__global__ void __launch_bounds__(256) k_mix_whh(
    const float* __restrict__ Whh_f, const float* __restrict__ Whh_r,
    const float* __restrict__ bias_f, const float* __restrict__ bias_r,
    const float* __restrict__ coef, u32* __restrict__ blobA, u32* __restrict__ blobB,
    float* __restrict__ bias_m)
{
  int gblk = blockIdx.x;   // 0..127, 8 gates each
  int dir  = blockIdx.y;
  int tid  = threadIdx.x;
  const float* Wsel = dir ? Whh_r : Whh_f;
  const float* bsel = dir ? bias_r : bias_f;
  __shared__ float bs[N_][8][H_];   // 64 KB
  for (int v = 0; v < 64; ++v){
    int i = v*256 + tid;
    int n = i >> 11, gl = (i >> 8) & 7, c = i & 255;
    bs[n][gl][c] = Wsel[((size_t)n*G_ + gblk*8 + gl)*H_ + c];
  }
  __syncthreads();
  float bw0[4][8], bw1[4][8];
  int glv[4], pv[4];
  #pragma unroll
  for (int u = 0; u < 4; ++u){
    int pi = u*256 + tid;           // 0..1023 = gate_local(8) x pair(128)
    int gl = pi >> 7, p = pi & 127;
    glv[u] = gl; pv[u] = p;
    #pragma unroll
    for (int n = 0; n < 8; ++n){ bw0[u][n] = bs[n][gl][2*p]; bw1[u][n] = bs[n][gl][2*p+1]; }
  }
  for (int b = 0; b < B_; ++b){
    float c8[8];
    #pragma unroll
    for (int n = 0; n < 8; ++n) c8[n] = coef[b*8+n];
    int chain = dir*B_ + b;
    #pragma unroll
    for (int u = 0; u < 4; ++u){
      float w0 = 0.f, w1 = 0.f;
      #pragma unroll
      for (int n = 0; n < 8; ++n){ w0 = fmaf(c8[n], bw0[u][n], w0); w1 = fmaf(c8[n], bw1[u][n], w1); }
      u32 pk = pkf16(w0, w1);
      int gate = gblk*8 + glv[u], p = pv[u];
      if (p < 96){
        int k = 2*p + (gate & 1);
        blobA[((((size_t)chain*48 + (k>>2))*512) + (gate>>1))*4 + (k&3)] = pk;
      } else {
        blobB[((size_t)chain*32 + (p-96))*1024 + gate] = pk;
      }
    }
    if (tid < 8){
      float bb = 0.f;
      #pragma unroll
      for (int n = 0; n < 8; ++n) bb = fmaf(c8[n], bsel[n*G_ + gblk*8 + tid], bb);
      bias_m[(size_t)chain*G_ + gblk*8 + tid] = bb;
    }
  }
}

// ---------------- K2b: mix Wih into bf16 [dir][b][g][320] (zero-padded) ----------------
__global__ void __launch_bounds__(256) k_mix_wi(
    const float* __restrict__ Wih_f, const float* __restrict__ Wih_r,
    const float* __restrict__ coef, u32* __restrict__ WimU)
{
  int gblk = blockIdx.x;
  int dir  = blockIdx.y;
  int tid  = threadIdx.x;
  const float* Wsel = dir ? Wih_r : Wih_f;
  __shared__ float bs[N_][8][D_];   // 76.8 KB
  for (int v = 0; v < 75; ++v){
    int i = v*256 + tid;            // < 19200
    int n = i/2400, rem = i%2400, gl = rem/300, c = rem%300;
    bs[n][gl][c] = Wsel[((size_t)n*G_ + gblk*8 + gl)*D_ + c];
  }
  __syncthreads();
  float bw[5][2][8];
  int rowv[5], cpv[5];
  #pragma unroll
  for (int v = 0; v < 5; ++v){
    int idx = v*256 + tid;          // < 1280
    int row = idx/160, cp = idx%160;
    rowv[v] = row; cpv[v] = cp;
    #pragma unroll
    for (int n = 0; n < 8; ++n){
      bw[v][0][n] = (cp < 150) ? bs[n][row][2*cp]   : 0.f;
      bw[v][1][n] = (cp < 150) ? bs[n][row][2*cp+1] : 0.f;
    }
  }
  for (int b = 0; b < B_; ++b){
    float c8[8];
    #pragma unroll
    for (int n = 0; n < 8; ++n) c8[n] = coef[b*8+n];
    #pragma unroll
    for (int v = 0; v < 5; ++v){
      float w0 = 0.f, w1 = 0.f;
      #pragma unroll
      for (int n = 0; n < 8; ++n){ w0 = fmaf(c8[n], bw[v][0][n], w0); w1 = fmaf(c8[n], bw[v][1][n], w1); }
      WimU[(((size_t)(dir*B_+b)*G_ + gblk*8 + rowv[v])*160) + cpv[v]] = (u32)f2bf(w0) | ((u32)f2bf(w1) << 16);
    }
  }
}

// ---------------- K2c: x -> bf16, padded to 320 ----------------
__global__ void __launch_bounds__(256) k_xpad(const float* __restrict__ x, u32* __restrict__ xpadU)
{
  int o = blockIdx.x*256 + threadIdx.x;   // < 64*256*160
  int bt = o/160, cp = o%160;
  float v0 = (cp < 150) ? x[(size_t)bt*D_ + 2*cp]   : 0.f;
  float v1 = (cp < 150) ? x[(size_t)bt*D_ + 2*cp+1] : 0.f;
  xpadU[o] = (u32)f2bf(v0) | ((u32)f2bf(v1) << 16);
}

// ---------------- K3: xproj[dir][b][t][g] (bf16) = xpad[b] @ Wim[dir][b]^T ----------------
__global__ void __launch_bounds__(256,2) k_gemm(
    const u16* __restrict__ xpad, const u16* __restrict__ Wim, u16* __restrict__ xproj)
{
  int bx = blockIdx.x;
  int b  = blockIdx.y, dir = blockIdx.z;
  int tt = bx >> 3, tg = bx & 7;
  int tid = threadIdx.x;
  int wid = tid >> 6, lane = tid & 63;
  int wr = wid >> 1, wc = wid & 1;
  __shared__ u16 As[128][72];
  __shared__ u16 Bs[128][72];
  const u16* Ap = xpad + ((size_t)b*T_ + tt*128)*DP_;
  const u16* Bp = Wim + (((size_t)dir*B_ + b)*G_ + tg*128)*DP_;
  f32x4 acc[4][4];
  #pragma unroll
  for (int i = 0; i < 4; ++i)
    #pragma unroll
    for (int j = 0; j < 4; ++j) acc[i][j] = (f32x4){0.f,0.f,0.f,0.f};
  for (int kt = 0; kt < 5; ++kt){
    int k0 = kt*64;
    #pragma unroll
    for (int i = 0; i < 4; ++i){
      int ci = i*256 + tid;
      int row = ci >> 3, cc = (ci & 7)*8;
      *(u32x4*)&As[row][cc] = *(const u32x4*)(Ap + (size_t)row*DP_ + k0 + cc);
      *(u32x4*)&Bs[row][cc] = *(const u32x4*)(Bp + (size_t)row*DP_ + k0 + cc);
    }
    __syncthreads();
    #pragma unroll
    for (int kk = 0; kk < 2; ++kk){
      short8 af[4], bfr[4];
      #pragma unroll
      for (int mi = 0; mi < 4; ++mi) af[mi]  = *(const short8*)&As[wr*64 + mi*16 + (lane&15)][kk*32 + (lane>>4)*8];
      #pragma unroll
      for (int ni = 0; ni < 4; ++ni) bfr[ni] = *(const short8*)&Bs[wc*64 + ni*16 + (lane&15)][kk*32 + (lane>>4)*8];
      #pragma unroll
      for (int mi = 0; mi < 4; ++mi)
        #pragma unroll
        for (int ni = 0; ni < 4; ++ni)
          acc[mi][ni] = __builtin_amdgcn_mfma_f32_16x16x32_bf16(af[mi], bfr[ni], acc[mi][ni], 0,0,0);
    }
    __syncthreads();
  }
  int r4 = (lane >> 4)*4, cg = lane & 15;
  #pragma unroll
  for (int mi = 0; mi < 4; ++mi)
    #pragma unroll
    for (int ni = 0; ni < 4; ++ni)
      #pragma unroll
      for (int j = 0; j < 4; ++j){
        int t = tt*128 + wr*64 + mi*16 + r4 + j;
        int g = tg*128 + wc*64 + ni*16 + cg;
        xproj[(((size_t)dir*B_ + b)*T_ + t)*G_ + g] = f2bf(acc[mi][ni][j]);
      }
}

// ---------------- K4: recurrence, one chain (b,dir) per workgroup ----------------
// 512 threads, thread tid owns gates (2*tid, 2*tid+1).
// Weights: cols 0..191 (pairs 0..95) in VGPRs (f16 pairs), cols 192..255 in LDS.
__global__ void __launch_bounds__(512,1) k_rec(
    const u32* __restrict__ blobA, const u32* __restrict__ blobB,
    const float* __restrict__ bias_m, const u32* __restrict__ xprojU,
    const int* __restrict__ length, float* __restrict__ out)
{
  int chain = blockIdx.x;
  int dir = chain >> 6, b = chain & 63;
  int tid = threadIdx.x;
  __shared__ u32 wlds[32][1024];   // 128 KB: pairs 96..127, all 1024 gates
  __shared__ float gates[1024];    // 4 KB
  __shared__ float c_lds[256];     // 1 KB
  __shared__ u32 hp[128];          // 0.5 KB: h as packed f16 pairs

  u32 wA[96], wB[96];
  #pragma unroll
  for (int i = 0; i < 48; ++i){
    u32x4 v = *(const u32x4*)(blobA + ((((size_t)chain*48 + i)*512) + tid)*4);
    wA[2*i] = v.x; wB[2*i] = v.y; wA[2*i+1] = v.z; wB[2*i+1] = v.w;
  }
  const u32* pb = blobB + (size_t)chain*32768;
  #pragma unroll
  for (int q = 0; q < 32; ++q){
    u32x2 v = *(const u32x2*)(pb + q*1024 + 2*tid);
    *(u32x2*)&wlds[q][2*tid] = v;
  }
  float2 bb = *(const float2*)&bias_m[(size_t)chain*G_ + 2*tid];
  if (tid < 128) hp[tid] = 0u;
  if (tid < 256) c_lds[tid] = 0.f;
  int len = length[b];
  const u32* xp = xprojU + (size_t)chain*T_*512;
  float* outp = out + ((size_t)b*T_)*512 + dir*H_;
  __syncthreads();

  for (int step = 0; step < len; ++step){
    int t = dir ? (len-1-step) : step;
    u32 xv = xp[(size_t)t*512 + tid];   // issued early; used after dot chain
    float a0 = bb.x, a1 = bb.y;
    #pragma unroll
    for (int cb = 0; cb < 24; ++cb){
      u32x4 hc = *(const u32x4*)&hp[cb*4];
      a0 = fdot2(wA[cb*4+0], hc.x, a0); a1 = fdot2(wB[cb*4+0], hc.x, a1);
      a0 = fdot2(wA[cb*4+1], hc.y, a0); a1 = fdot2(wB[cb*4+1], hc.y, a1);
      a0 = fdot2(wA[cb*4+2], hc.z, a0); a1 = fdot2(wB[cb*4+2], hc.z, a1);
      a0 = fdot2(wA[cb*4+3], hc.w, a0); a1 = fdot2(wB[cb*4+3], hc.w, a1);
    }
    #pragma unroll
    for (int cb = 0; cb < 8; ++cb){
      u32x4 hc = *(const u32x4*)&hp[96 + cb*4];
      #pragma unroll
      for (int e = 0; e < 4; ++e){
        int q = cb*4 + e;
        u32x2 wv = *(const u32x2*)&wlds[q][2*tid];
        u32 hcv = (e==0) ? hc.x : (e==1) ? hc.y : (e==2) ? hc.z : hc.w;
        a0 = fdot2(wv.x, hcv, a0); a1 = fdot2(wv.y, hcv, a1);
      }
    }
    a0 += bflo(xv); a1 += bfhi(xv);
    float2 g2; g2.x = a0; g2.y = a1;
    *(float2*)&gates[2*tid] = g2;
    __syncthreads();
    if (tid < 128){
      int u0 = 2*tid, u1 = u0 + 1;
      float i0 = gates[u0],     i1 = gates[u1];
      float f0 = gates[256+u0], f1 = gates[256+u1];
      float g0 = gates[512+u0], g1 = gates[512+u1];
      float o0 = gates[768+u0], o1 = gates[768+u1];
      float c0 = fmaf(sigm(f0), c_lds[u0], sigm(i0)*tanh_(g0));
      float c1 = fmaf(sigm(f1), c_lds[u1], sigm(i1)*tanh_(g1));
      float h0 = sigm(o0)*tanh_(c0);
      float h1 = sigm(o1)*tanh_(c1);
      c_lds[u0] = c0; c_lds[u1] = c1;
      hp[tid] = pkf16(h0, h1);
      float2 ho; ho.x = h0; ho.y = h1;
      *(float2*)&outp[(size_t)t*512 + u0] = ho;
    }
    __syncthreads();
  }
}

extern "C" void kernel_launch(void* const* d_in, const int* in_sizes, int n_in,
                              void* d_out, int out_size, void* d_ws, size_t ws_size,
                              hipStream_t stream)
{
  const float* x      = (const float*)d_in[0];
  const int*   length = (const int*)d_in[1];
  const int*   uidx   = (const int*)d_in[2];
  const int*   iidx   = (const int*)d_in[3];
  const float* uemb   = (const float*)d_in[4];
  const float* iemb   = (const float*)d_in[5];
  const float* W1     = (const float*)d_in[6];
  const float* b1     = (const float*)d_in[7];
  const float* W2     = (const float*)d_in[8];
  const float* Wih    = (const float*)d_in[9];
  const float* Whh    = (const float*)d_in[10];
  const float* bias   = (const float*)d_in[11];
  const float* Wih_r  = (const float*)d_in[12];
  const float* Whh_r  = (const float*)d_in[13];
  const float* bias_r = (const float*)d_in[14];
  float* out = (float*)d_out;
  char* ws = (char*)d_ws;

  float* coef   = (float*)(ws + 0);              //      2,048
  float* bias_m = (float*)(ws + 2048);           //    524,288
  u32*   blobA  = (u32*)  (ws + 526336);         // 50,331,648  (128*512*192*4)
  u32*   blobB  = (u32*)  (ws + 50857984);       // 16,777,216  (128*32*1024*4)
  u16*   Wim    = (u16*)  (ws + 67635200);       // 83,886,080
  u16*   xpad   = (u16*)  (ws + 151521280);      // 10,485,760
  u16*   xproj  = (u16*)  (ws + 162007040);      // 67,108,864  -> total 229,115,904

  (void)hipMemsetAsync(d_out, 0, (size_t)out_size*sizeof(float), stream);
  if (ws_size < 229115904ull) return;  // fail loudly (all-zero output) if workspace too small

  hipLaunchKernelGGL(k_coef,    dim3(64),       dim3(64),  0, stream, uidx, iidx, uemb, iemb, W1, b1, W2, coef);
  hipLaunchKernelGGL(k_mix_whh, dim3(128,2),    dim3(256), 0, stream, Whh, Whh_r, bias, bias_r, coef, blobA, blobB, bias_m);
  hipLaunchKernelGGL(k_mix_wi,  dim3(128,2),    dim3(256), 0, stream, Wih, Wih_r, coef, (u32*)Wim);
  hipLaunchKernelGGL(k_xpad,    dim3(10240),    dim3(256), 0, stream, x, (u32*)xpad);
  hipLaunchKernelGGL(k_gemm,    dim3(16,64,2),  dim3(256), 0, stream, xpad, Wim, xproj);
  hipLaunchKernelGGL(k_rec,     dim3(128),      dim3(512), 0, stream, blobA, blobB, bias_m, (const u32*)xproj, length, out);
}

// Round 4
// 623.316 us; speedup vs baseline: 7.3122x; 1.3684x over previous
//
#include <hip/hip_runtime.h>

#define B_ 64
#define T_ 256
#define D_ 300
#define DP_ 320
#define H_ 256
#define G_ 1024
#define N_ 8

typedef unsigned int u32;
typedef unsigned short u16;
typedef __attribute__((ext_vector_type(8))) short short8;
typedef __attribute__((ext_vector_type(4))) float f32x4;
typedef __attribute__((ext_vector_type(4))) u32 u32x4;
typedef __attribute__((ext_vector_type(2))) u32 u32x2;
typedef _Float16 h2 __attribute__((ext_vector_type(2)));
typedef __fp16 fp16x2 __attribute__((ext_vector_type(2)));

__device__ __forceinline__ u16 f2bf(float f){
  union {float f; u32 u;} v; v.f = f;
  u32 r = (v.u + 0x7fffu + ((v.u>>16)&1u)) >> 16;
  return (u16)r;
}
__device__ __forceinline__ float bflo(u32 u){
  union {u32 u; float f;} v; v.u = u<<16; return v.f;
}
__device__ __forceinline__ float bfhi(u32 u){
  union {u32 u; float f;} v; v.u = u & 0xffff0000u; return v.f;
}
__device__ __forceinline__ float sigm(float x){ return 1.0f/(1.0f+__expf(-x)); }
__device__ __forceinline__ float tanh_(float x){ return 2.0f/(1.0f+__expf(-2.0f*x)) - 1.0f; }

__device__ __forceinline__ float fdot2(u32 a, u32 b, float c){
  union { u32 u; h2 h; } ua, ub; ua.u = a; ub.u = b;
#if __has_builtin(__builtin_amdgcn_fdot2)
  return __builtin_amdgcn_fdot2(ua.h, ub.h, c, false);
#else
  return c + (float)ua.h.x*(float)ub.h.x + (float)ua.h.y*(float)ub.h.y;
#endif
}
__device__ __forceinline__ u32 pkf16(float a, float b){
  union { fp16x2 h; u32 u; } v; v.h = __builtin_amdgcn_cvt_pkrtz(a, b); return v.u;
}

// ---------------- K1: mixture coefficients c[b][8] ----------------
__global__ void __launch_bounds__(64) k_coef(
    const int* __restrict__ uidx, const int* __restrict__ iidx,
    const float* __restrict__ uemb, const float* __restrict__ iemb,
    const float* __restrict__ W1, const float* __restrict__ b1,
    const float* __restrict__ W2, float* __restrict__ coef)
{
  __shared__ float q[128];
  __shared__ float hid[64];
  __shared__ float lg[8];
  int b = blockIdx.x, t = threadIdx.x;
  int u = uidx[b], it = iidx[b];
  q[t]      = uemb[(size_t)u*64 + t];
  q[64 + t] = iemb[(size_t)it*64 + t];
  __syncthreads();
  float s = b1[t];
  for (int j = 0; j < 128; ++j) s = fmaf(q[j], W1[j*64 + t], s);
  hid[t] = tanhf(s);
  __syncthreads();
  if (t < 8) {
    float s2 = 0.f;
    for (int j = 0; j < 64; ++j) s2 = fmaf(hid[j], W2[j*8 + t], s2);
    lg[t] = s2;
  }
  __syncthreads();
  if (t == 0) {
    float mx = lg[0];
    for (int n = 1; n < 8; ++n) mx = fmaxf(mx, lg[n]);
    float e[8], den = 0.f;
    for (int n = 0; n < 8; ++n){ e[n] = __expf(lg[n]-mx); den += e[n]; }
    for (int n = 0; n < 8; ++n) coef[b*8+n] = e[n]/den;
  }
}

// ---------------- K2a: mix Whh (+bias) into packed f16 blob ----------------
// k_rec decomposition: thread tid2 = gg*4 + q (gg in [0,256): gates 4gg..4gg+3;
// q in [0,4): col pairs p in [32q, 32q+32)). Per-thread slots i in [0,128):
//   i = cidx*16 + e*4 + l  -> gate 4gg+l, pair p = q*32 + ((cidx+2q)&7)*4 + e.
// blob layout: [chain][i>>2 (32)][tid2 (1024)][i&3] u32 = 64 MB.
__global__ void __launch_bounds__(256) k_mix_whh(
    const float* __restrict__ Whh_f, const float* __restrict__ Whh_r,
    const float* __restrict__ bias_f, const float* __restrict__ bias_r,
    const float* __restrict__ coef, u32* __restrict__ blob, float* __restrict__ bias_m)
{
  int gblk = blockIdx.x;   // 0..127: gates [gblk*8, gblk*8+8) == tid2 [gblk*8, gblk*8+8)
  int dir  = blockIdx.y;
  int tid  = threadIdx.x;  // = ii*8 + t2l
  const float* Wsel = dir ? Whh_r : Whh_f;
  const float* bsel = dir ? bias_r : bias_f;
  __shared__ float bs[N_][8][H_];   // 64 KB
  for (int v = 0; v < 64; ++v){
    int i = v*256 + tid;
    int n = i >> 11, gl = (i >> 8) & 7, c = i & 255;
    bs[n][gl][c] = Wsel[((size_t)n*G_ + gblk*8 + gl)*H_ + c];
  }
  __syncthreads();
  int t2l = tid & 7, ii = tid >> 3;   // t2l in [0,8), ii in [0,32)
  int tid2 = gblk*8 + t2l;
  int gg = tid2 >> 2, q = tid2 & 3;
  int cidx = ii >> 2, e = ii & 3;
  int p = q*32 + ((cidx + 2*q)&7)*4 + e;     // this thread's column-pair
  int glbase = gg*4 - gblk*8;                 // 0 or 4
  float bw0[4][8], bw1[4][8];
  #pragma unroll
  for (int l = 0; l < 4; ++l)
    #pragma unroll
    for (int n = 0; n < 8; ++n){
      bw0[l][n] = bs[n][glbase + l][2*p];
      bw1[l][n] = bs[n][glbase + l][2*p + 1];
    }
  for (int b = 0; b < B_; ++b){
    float c8[8];
    #pragma unroll
    for (int n = 0; n < 8; ++n) c8[n] = coef[b*8+n];
    u32x4 ov;
    #pragma unroll
    for (int l = 0; l < 4; ++l){
      float w0 = 0.f, w1 = 0.f;
      #pragma unroll
      for (int n = 0; n < 8; ++n){ w0 = fmaf(c8[n], bw0[l][n], w0); w1 = fmaf(c8[n], bw1[l][n], w1); }
      ov[l] = pkf16(w0, w1);
    }
    size_t chain = (size_t)(dir*B_ + b);
    *(u32x4*)(blob + ((chain*32 + ii)*1024 + tid2)*4) = ov;
    if (tid < 8){
      float bb = 0.f;
      #pragma unroll
      for (int n = 0; n < 8; ++n) bb = fmaf(c8[n], bsel[n*G_ + gblk*8 + tid], bb);
      bias_m[chain*G_ + gblk*8 + tid] = bb;
    }
  }
}

// ---------------- K2b: mix Wih into bf16 [dir][b][g][320] (zero-padded) ----------------
__global__ void __launch_bounds__(256) k_mix_wi(
    const float* __restrict__ Wih_f, const float* __restrict__ Wih_r,
    const float* __restrict__ coef, u32* __restrict__ WimU)
{
  int gblk = blockIdx.x;
  int dir  = blockIdx.y;
  int tid  = threadIdx.x;
  const float* Wsel = dir ? Wih_r : Wih_f;
  __shared__ float bs[N_][8][D_];   // 76.8 KB
  for (int v = 0; v < 75; ++v){
    int i = v*256 + tid;            // < 19200
    int n = i/2400, rem = i%2400, gl = rem/300, c = rem%300;
    bs[n][gl][c] = Wsel[((size_t)n*G_ + gblk*8 + gl)*D_ + c];
  }
  __syncthreads();
  float bw[5][2][8];
  int rowv[5], cpv[5];
  #pragma unroll
  for (int v = 0; v < 5; ++v){
    int idx = v*256 + tid;          // < 1280
    int row = idx/160, cp = idx%160;
    rowv[v] = row; cpv[v] = cp;
    #pragma unroll
    for (int n = 0; n < 8; ++n){
      bw[v][0][n] = (cp < 150) ? bs[n][row][2*cp]   : 0.f;
      bw[v][1][n] = (cp < 150) ? bs[n][row][2*cp+1] : 0.f;
    }
  }
  for (int b = 0; b < B_; ++b){
    float c8[8];
    #pragma unroll
    for (int n = 0; n < 8; ++n) c8[n] = coef[b*8+n];
    #pragma unroll
    for (int v = 0; v < 5; ++v){
      float w0 = 0.f, w1 = 0.f;
      #pragma unroll
      for (int n = 0; n < 8; ++n){ w0 = fmaf(c8[n], bw[v][0][n], w0); w1 = fmaf(c8[n], bw[v][1][n], w1); }
      WimU[(((size_t)(dir*B_+b)*G_ + gblk*8 + rowv[v])*160) + cpv[v]] = (u32)f2bf(w0) | ((u32)f2bf(w1) << 16);
    }
  }
}

// ---------------- K2c: x -> bf16, padded to 320 ----------------
__global__ void __launch_bounds__(256) k_xpad(const float* __restrict__ x, u32* __restrict__ xpadU)
{
  int o = blockIdx.x*256 + threadIdx.x;   // < 64*256*160
  int bt = o/160, cp = o%160;
  float v0 = (cp < 150) ? x[(size_t)bt*D_ + 2*cp]   : 0.f;
  float v1 = (cp < 150) ? x[(size_t)bt*D_ + 2*cp+1] : 0.f;
  xpadU[o] = (u32)f2bf(v0) | ((u32)f2bf(v1) << 16);
}

// ---------------- K3: xproj[dir][b][t][g] (bf16) = xpad[b] @ Wim[dir][b]^T + bias ----------------
__global__ void __launch_bounds__(256,2) k_gemm(
    const u16* __restrict__ xpad, const u16* __restrict__ Wim,
    const float* __restrict__ bias_m, u16* __restrict__ xproj)
{
  int bx = blockIdx.x;
  int b  = blockIdx.y, dir = blockIdx.z;
  int tt = bx >> 3, tg = bx & 7;
  int tid = threadIdx.x;
  int wid = tid >> 6, lane = tid & 63;
  int wr = wid >> 1, wc = wid & 1;
  __shared__ u16 As[128][72];
  __shared__ u16 Bs[128][72];
  const u16* Ap = xpad + ((size_t)b*T_ + tt*128)*DP_;
  const u16* Bp = Wim + (((size_t)dir*B_ + b)*G_ + tg*128)*DP_;
  f32x4 acc[4][4];
  #pragma unroll
  for (int i = 0; i < 4; ++i)
    #pragma unroll
    for (int j = 0; j < 4; ++j) acc[i][j] = (f32x4){0.f,0.f,0.f,0.f};
  for (int kt = 0; kt < 5; ++kt){
    int k0 = kt*64;
    #pragma unroll
    for (int i = 0; i < 4; ++i){
      int ci = i*256 + tid;
      int row = ci >> 3, cc = (ci & 7)*8;
      *(u32x4*)&As[row][cc] = *(const u32x4*)(Ap + (size_t)row*DP_ + k0 + cc);
      *(u32x4*)&Bs[row][cc] = *(const u32x4*)(Bp + (size_t)row*DP_ + k0 + cc);
    }
    __syncthreads();
    #pragma unroll
    for (int kk = 0; kk < 2; ++kk){
      short8 af[4], bfr[4];
      #pragma unroll
      for (int mi = 0; mi < 4; ++mi) af[mi]  = *(const short8*)&As[wr*64 + mi*16 + (lane&15)][kk*32 + (lane>>4)*8];
      #pragma unroll
      for (int ni = 0; ni < 4; ++ni) bfr[ni] = *(const short8*)&Bs[wc*64 + ni*16 + (lane&15)][kk*32 + (lane>>4)*8];
      #pragma unroll
      for (int mi = 0; mi < 4; ++mi)
        #pragma unroll
        for (int ni = 0; ni < 4; ++ni)
          acc[mi][ni] = __builtin_amdgcn_mfma_f32_16x16x32_bf16(af[mi], bfr[ni], acc[mi][ni], 0,0,0);
    }
    __syncthreads();
  }
  int r4 = (lane >> 4)*4, cg = lane & 15;
  const float* bmp = bias_m + (size_t)(dir*B_ + b)*G_;
  #pragma unroll
  for (int ni = 0; ni < 4; ++ni){
    int g = tg*128 + wc*64 + ni*16 + cg;
    float bsv = bmp[g];
    #pragma unroll
    for (int mi = 0; mi < 4; ++mi)
      #pragma unroll
      for (int j = 0; j < 4; ++j){
        int t = tt*128 + wr*64 + mi*16 + r4 + j;
        xproj[(((size_t)dir*B_ + b)*T_ + t)*G_ + g] = f2bf(acc[mi][ni][j] + bsv);
      }
  }
}

// ---------------- K4: recurrence, one chain (b,dir) per workgroup ----------------
// 1024 threads: tid = gg*4 + q. gg owns gates 4gg..4gg+3; q owns col pairs [32q,32q+32).
// 128 dot2/thread/step on 4 accumulators; quad shfl_xor butterfly reduces k-slices.
// Weights: slots 0..95 in VGPRs, slots 96..127 in LDS (128 KB).
__global__ void __launch_bounds__(1024) k_rec(
    const u32* __restrict__ blob, const u32* __restrict__ xprojU,
    const int* __restrict__ length, float* __restrict__ out)
{
  int chain = blockIdx.x;
  int dir = chain >> 6, b = chain & 63;
  int tid = threadIdx.x;
  int gg = tid >> 2, q = tid & 3;
  __shared__ u32 wlds[8][1024][4];            // 128 KB: slot-quads 24..31
  __shared__ __align__(16) float gates4[256][4]; // 4 KB: gates4[gg][l] = gate 4gg+l
  __shared__ __align__(16) u16 hp16[256];     // 512 B: h as f16
  const u32* hp32 = (const u32*)hp16;

  u32 w[96];
  const u32* bp = blob + (size_t)chain*32*1024*4;
  #pragma unroll
  for (int ii = 0; ii < 24; ++ii){
    u32x4 v = *(const u32x4*)(bp + ((size_t)ii*1024 + tid)*4);
    w[4*ii] = v.x; w[4*ii+1] = v.y; w[4*ii+2] = v.z; w[4*ii+3] = v.w;
  }
  #pragma unroll
  for (int ii = 24; ii < 32; ++ii){
    u32x4 v = *(const u32x4*)(bp + ((size_t)ii*1024 + tid)*4);
    *(u32x4*)&wlds[ii-24][tid][0] = v;
  }
  if (tid < 256) hp16[tid] = 0;
  int len = length[b];
  const u32* xp = xprojU + (size_t)chain*T_*512;
  float* outp = out + (size_t)b*T_*512 + dir*H_;
  float cst = 0.f;
  __syncthreads();

  for (int step = 0; step < len; ++step){
    int t = dir ? (len-1-step) : step;
    u32 xv0 = 0, xv1 = 0;
    if (q == 0){
      u32x2 xv = *(const u32x2*)(xp + (size_t)t*512 + 2*gg);
      xv0 = xv.x; xv1 = xv.y;
    }
    float a0 = 0.f, a1 = 0.f, a2 = 0.f, a3 = 0.f;
    #pragma unroll
    for (int cidx = 0; cidx < 8; ++cidx){
      int c4 = (cidx + 2*q) & 7;
      u32x4 hq = *(const u32x4*)&hp32[q*32 + c4*4];
      if (cidx < 6){
        #pragma unroll
        for (int e = 0; e < 4; ++e){
          u32 hv = hq[e];
          a0 = fdot2(w[cidx*16 + e*4 + 0], hv, a0);
          a1 = fdot2(w[cidx*16 + e*4 + 1], hv, a1);
          a2 = fdot2(w[cidx*16 + e*4 + 2], hv, a2);
          a3 = fdot2(w[cidx*16 + e*4 + 3], hv, a3);
        }
      } else {
        #pragma unroll
        for (int e = 0; e < 4; ++e){
          u32x4 wv = *(const u32x4*)&wlds[cidx*4 + e - 24][tid][0];
          u32 hv = hq[e];
          a0 = fdot2(wv.x, hv, a0);
          a1 = fdot2(wv.y, hv, a1);
          a2 = fdot2(wv.z, hv, a2);
          a3 = fdot2(wv.w, hv, a3);
        }
      }
    }
    // reduce over q (quad butterfly)
    a0 += __shfl_xor(a0, 1); a0 += __shfl_xor(a0, 2);
    a1 += __shfl_xor(a1, 1); a1 += __shfl_xor(a1, 2);
    a2 += __shfl_xor(a2, 1); a2 += __shfl_xor(a2, 2);
    a3 += __shfl_xor(a3, 1); a3 += __shfl_xor(a3, 2);
    if (q == 0){
      a0 += bflo(xv0); a1 += bfhi(xv0); a2 += bflo(xv1); a3 += bfhi(xv1);
      f32x4 g4; g4.x = a0; g4.y = a1; g4.z = a2; g4.w = a3;
      *(f32x4*)&gates4[gg][0] = g4;
    }
    __syncthreads();
    if (tid < 256){
      const float* gf = &gates4[0][0];   // gf[g] = gate g
      float ig = gf[tid],       fg = gf[256 + tid];
      float g_ = gf[512 + tid], og = gf[768 + tid];
      float i_ = sigm(ig), f_ = sigm(fg), gt = tanh_(g_), o_ = sigm(og);
      float cn = fmaf(f_, cst, i_*gt);
      float hy = o_ * tanh_(cn);
      cst = cn;
      ((u16*)hp16)[tid] = (u16)(pkf16(hy, hy) & 0xffffu);
      outp[(size_t)t*512 + tid] = hy;
    }
    __syncthreads();
  }
}

extern "C" void kernel_launch(void* const* d_in, const int* in_sizes, int n_in,
                              void* d_out, int out_size, void* d_ws, size_t ws_size,
                              hipStream_t stream)
{
  const float* x      = (const float*)d_in[0];
  const int*   length = (const int*)d_in[1];
  const int*   uidx   = (const int*)d_in[2];
  const int*   iidx   = (const int*)d_in[3];
  const float* uemb   = (const float*)d_in[4];
  const float* iemb   = (const float*)d_in[5];
  const float* W1     = (const float*)d_in[6];
  const float* b1     = (const float*)d_in[7];
  const float* W2     = (const float*)d_in[8];
  const float* Wih    = (const float*)d_in[9];
  const float* Whh    = (const float*)d_in[10];
  const float* bias   = (const float*)d_in[11];
  const float* Wih_r  = (const float*)d_in[12];
  const float* Whh_r  = (const float*)d_in[13];
  const float* bias_r = (const float*)d_in[14];
  float* out = (float*)d_out;
  char* ws = (char*)d_ws;

  float* coef   = (float*)(ws + 0);              //      2,048
  float* bias_m = (float*)(ws + 2048);           //    524,288
  u32*   blob   = (u32*)  (ws + 526336);         // 67,108,864 region (64 MB used)
  u16*   Wim    = (u16*)  (ws + 67635200);       // 83,886,080
  u16*   xpad   = (u16*)  (ws + 151521280);      // 10,485,760
  u16*   xproj  = (u16*)  (ws + 162007040);      // 67,108,864  -> total 229,115,904

  (void)hipMemsetAsync(d_out, 0, (size_t)out_size*sizeof(float), stream);
  if (ws_size < 229115904ull) return;  // fail loudly (all-zero output) if workspace too small

  hipLaunchKernelGGL(k_coef,    dim3(64),       dim3(64),   0, stream, uidx, iidx, uemb, iemb, W1, b1, W2, coef);
  hipLaunchKernelGGL(k_mix_whh, dim3(128,2),    dim3(256),  0, stream, Whh, Whh_r, bias, bias_r, coef, blob, bias_m);
  hipLaunchKernelGGL(k_mix_wi,  dim3(128,2),    dim3(256),  0, stream, Wih, Wih_r, coef, (u32*)Wim);
  hipLaunchKernelGGL(k_xpad,    dim3(10240),    dim3(256),  0, stream, x, (u32*)xpad);
  hipLaunchKernelGGL(k_gemm,    dim3(16,64,2),  dim3(256),  0, stream, xpad, Wim, bias_m, xproj);
  hipLaunchKernelGGL(k_rec,     dim3(128),      dim3(1024), 0, stream, blob, (const u32*)xproj, length, out);
}